// Round 19
// baseline (18.584 us; speedup 1.0000x reference)
//
#include <hip/hip_runtime.h>
#include <math.h>

constexpr int IMG = 224;
constexpr int Bb  = 16;
constexpr int Vv  = 8;
constexpr int Nn  = 8192;
constexpr int Mm  = 1024;
constexpr int G   = 32;                 // bins per axis
constexpr float Hh = 1.0f / 32.0f;      // cell size, normalized coords

// Fused kernel, 256 blocks (1/CU) x 512 threads. R18 structure plus XCD
// locality: grid = (batch, chunk) so the 16 blocks of a batch get linear ids
// === batch (mod 16) -> all on XCD batch%8; each XCD caches its 2 batches'
// mask/bounds/proj working set (~3 MB) in its private 4 MB L2.
__global__ __launch_bounds__(512) void calib_kernel(
    const float* __restrict__ pc,         // (B, N, 3)
    const float* __restrict__ mask,       // (B, V, IMG, IMG)
    const float* __restrict__ bounds,     // (B, V, M, 2)
    const float* __restrict__ inv_param,  // (B, V, 4, 4)
    const float* __restrict__ proj_fine,  // (B, V, N, 2)
    const float* __restrict__ proj_finez, // (B, V, N)
    const int*   __restrict__ view_p,
    float*       __restrict__ out)        // (B, N, 3)
{
    const int view = *view_p;
    const int b = blockIdx.x;             // batch in x: same-batch blocks
    const int chunk = blockIdx.y;         // land on one XCD (id stride 16)
    const int t = threadIdx.x;
    const int lane = t & 63;
    const int w = t >> 6;                 // wave id, 0..7

    __shared__ float4 s_e[Mm];            // packed (bdx, bdy, |bd|^2, j)  16 KB
    __shared__ float2 s_raw[Mm];          // raw (bx, by) by candidate j    8 KB
    __shared__ int s_start[1025];         // cell -> range start
    __shared__ int s_cnt[1024];           // counts, then cursors
    __shared__ int s_wtot[8];

    // ---- early-issue ALL per-point global loads (hide under binning) -----
    const int i = chunk * 512 + t;
    const size_t pf = (size_t)(b * Vv + view) * Nn + i;
    float2 pxy = reinterpret_cast<const float2*>(proj_fine)[pf];
    float z    = proj_finez[pf];
    const size_t ob = ((size_t)b * Nn + i) * 3;
    float pc0 = pc[ob], pc1 = pc[ob + 1], pc2 = pc[ob + 2];

    // ---------------- phase 1: bin this batch's candidates ----------------
    #pragma unroll
    for (int u = 0; u < 2; ++u) s_cnt[t + 512 * u] = 0;
    __syncthreads();

    const float* bnd = bounds + (size_t)(b * Vv + view) * Mm * 2;
    float bdx[2], bdy[2];
    int cell[2];
    #pragma unroll
    for (int u = 0; u < 2; ++u) {
        int j = t + 512 * u;
        float2 bxy = reinterpret_cast<const float2*>(bnd)[j];
        s_raw[j] = bxy;                   // raw mirror (exact loaded bits)
        bdx[u] = bxy.x / (float)IMG;      // exact IEEE div, matches ref
        bdy[u] = bxy.y / (float)IMG;
        int cx = min(G - 1, max(0, (int)(bdx[u] * (float)G)));
        int cy = min(G - 1, max(0, (int)(bdy[u] * (float)G)));
        cell[u] = cy * G + cx;
        atomicAdd(&s_cnt[cell[u]], 1);
    }

    // mask probe between hist and barrier: pxy has arrived; the probe's
    // latency hides under scan + scatter (and is an L2 hit with the swizzle)
    int i0 = (int)rintf(pxy.x);                 // round half-to-even
    int i1 = (int)rintf((float)IMG - pxy.y);
    int xi = min(max(i1 + 1, 0), IMG + 1);
    int yi = min(max(i0 + 1, 0), IMG + 1);
    float mval = 0.0f;
    if (xi >= 1 && xi <= IMG && yi >= 1 && yi <= IMG)
        mval = mask[((size_t)(b * Vv + view) * IMG + (xi - 1)) * IMG + (yi - 1)];
    const bool use_back = (mval == 0.0f);
    __syncthreads();

    // prefix sum over 1024 cells: 2 serial/thread + wave shfl-scan + fixup
    int c0 = s_cnt[2 * t], c1 = s_cnt[2 * t + 1];
    int psum = c0 + c1;
    int incl = psum;
    #pragma unroll
    for (int off = 1; off < 64; off <<= 1) {
        int v = __shfl_up(incl, off);
        if (lane >= off) incl += v;
    }
    if (lane == 63) s_wtot[w] = incl;
    __syncthreads();
    int basew = 0;
    #pragma unroll
    for (int ww = 0; ww < 8; ++ww) basew += (ww < w) ? s_wtot[ww] : 0;
    int base = basew + incl - psum;       // exclusive start of cell 2t
    s_start[2 * t] = base;
    s_start[2 * t + 1] = base + c0;
    if (t == 0) s_start[1024] = Mm;
    s_cnt[2 * t] = base;
    s_cnt[2 * t + 1] = base + c0;
    __syncthreads();

    // scatter (intra-cell order atomic-arbitrary; lex (d2,j) reduction makes
    // the final result order-invariant => deterministic output)
    #pragma unroll
    for (int u = 0; u < 2; ++u) {
        int j = t + 512 * u;
        int pos = atomicAdd(&s_cnt[cell[u]], 1);
        float nrm = __fadd_rn(__fmul_rn(bdx[u], bdx[u]), __fmul_rn(bdy[u], bdy[u]));
        s_e[pos] = make_float4(bdx[u], bdy[u], nrm, __int_as_float(j));
    }
    __syncthreads();

    // ---------------- phase 2: one thread = one point ----------------------
    if (use_back) {
        float ox = (float)i0 / (float)IMG;
        float oy = (float)i1 / (float)IMG;
        float o2 = __fadd_rn(__fmul_rn(ox, ox), __fmul_rn(oy, oy));
        // exact power-of-2 scale; d2 bits identical to prior rounds
        float n2ox = __fmul_rn(-2.0f, ox);
        float n2oy = __fmul_rn(-2.0f, oy);

        int cx = min(G - 1, max(0, (int)(ox * (float)G)));
        int cy = min(G - 1, max(0, (int)(oy * (float)G)));

        float best = INFINITY;
        int   bj   = 0;

        // tier 1: full 5x5 window, serial per thread (visit order irrelevant)
        int x0 = max(cx - 2, 0), x1 = min(cx + 2, G - 1);
        int y0 = max(cy - 2, 0), y1 = min(cy + 2, G - 1);
        for (int yy = y0; yy <= y1; ++yy) {
            int rowb = yy * G;
            int e0 = s_start[rowb + x0];
            int e1 = s_start[rowb + x1 + 1];
            for (int e = e0; e < e1; ++e) {
                float4 cd = s_e[e];
                float dn = __fadd_rn(__fmul_rn(n2ox, cd.x), __fmul_rn(n2oy, cd.y));
                float d2 = __fadd_rn(__fadd_rn(o2, cd.z), dn);
                int   j  = __float_as_int(cd.w);
                bool better = (d2 < best) || (d2 == best && j < bj);
                best = better ? d2 : best;
                bj   = better ? j  : bj;
            }
        }

        // tier 2 (P~3e-6): serial ring walker, rings >= 3.
        // unvisited = Chebyshev cell-ring >= 3 => d >= 2h => d2 >= 4h^2-slop
        if (!(best < 4.0f * Hh * Hh - 1e-5f)) {
            for (int r = 3; r <= G; ++r) {
                float lim = (float)(r - 1) * Hh;
                if (best < lim * lim - 1e-5f) break;
                int rx0 = max(0, cx - r), rx1 = min(G - 1, cx + r);
                int ry0 = max(0, cy - r), ry1 = min(G - 1, cy + r);
                for (int yy = ry0; yy <= ry1; ++yy) {
                    bool yedge = (yy == cy - r) || (yy == cy + r);
                    for (int xx = rx0; xx <= rx1; ++xx) {
                        if (!yedge && xx != cx - r && xx != cx + r) continue;
                        int c = yy * G + xx;
                        int e0 = s_start[c], e1 = s_start[c + 1];
                        for (int e = e0; e < e1; ++e) {
                            float4 cd = s_e[e];
                            float dn = __fadd_rn(__fmul_rn(n2ox, cd.x), __fmul_rn(n2oy, cd.y));
                            float d2 = __fadd_rn(__fadd_rn(o2, cd.z), dn);
                            int   j  = __float_as_int(cd.w);
                            bool better = (d2 < best) || (d2 == best && j < bj);
                            best = better ? d2 : best;
                            bj   = better ? j  : bj;
                        }
                    }
                }
            }
        }

        // back-projection using the LDS raw mirror (same bits as bnd[2*bj])
        float2 nb = s_raw[bj];
        const float* ip = inv_param + (size_t)(b * Vv + view) * 16;
        float h0 = nb.x * z, h1 = nb.y * z;
        float r0 = h0 * ip[0] + h1 * ip[4] + z * ip[8]  + ip[12];
        float r1 = h0 * ip[1] + h1 * ip[5] + z * ip[9]  + ip[13];
        float r2 = h0 * ip[2] + h1 * ip[6] + z * ip[10] + ip[14];
        out[ob]     = r0;
        out[ob + 1] = r1;
        out[ob + 2] = r2;
    } else {
        out[ob]     = pc0;
        out[ob + 1] = pc1;
        out[ob + 2] = pc2;
    }
}

extern "C" void kernel_launch(void* const* d_in, const int* in_sizes, int n_in,
                              void* d_out, int out_size, void* d_ws, size_t ws_size,
                              hipStream_t stream) {
    const float* pc         = (const float*)d_in[0];
    const float* mask       = (const float*)d_in[1];
    const float* bounds     = (const float*)d_in[2];
    const float* inv_param  = (const float*)d_in[3];
    const float* proj_fine  = (const float*)d_in[4];
    const float* proj_finez = (const float*)d_in[5];
    const int*   view_p     = (const int*)d_in[6];
    float* out = (float*)d_out;

    // grid = (batch, chunk): same-batch blocks have linear ids === b (mod 16)
    // -> co-located on XCD b%8 (8 XCDs round-robin by linear id).
    dim3 grid(Bb, Nn / 512);
    calib_kernel<<<grid, 512, 0, stream>>>(pc, mask, bounds, inv_param,
                                           proj_fine, proj_finez, view_p, out);
}

// Round 20
// 18.473 us; speedup vs baseline: 1.0060x; 1.0060x over previous
//
#include <hip/hip_runtime.h>
#include <math.h>

constexpr int IMG = 224;
constexpr int Bb  = 16;
constexpr int Vv  = 8;
constexpr int Nn  = 8192;
constexpr int Mm  = 1024;
constexpr int G   = 32;                 // bins per axis
constexpr float Hh = 1.0f / 32.0f;      // cell size, normalized coords

// FINAL (best-measured, R18 = 18.47 us): fused single-launch kernel,
// 256 blocks (1/CU) x 512 threads. Per block: bin the batch's 1024
// candidates into a 32x32 LDS grid (hist + wave-shfl scan + packed scatter),
// then each thread searches one point via a 5x5-cell window with an exact
// ring-walker fallback (P~3e-6). All per-point global loads issue at kernel
// entry and the mask probe sits pre-barrier so their latency hides under
// binning; the epilogue reads bounds from an LDS raw mirror instead of a
// dependent global gather. d2 arithmetic is __fadd_rn/__fmul_rn-frozen in
// the numpy association; ties resolve lexicographically (d2, then smaller j)
// = numpy first-index argmin; result is candidate-visit-order invariant, so
// atomic scatter order cannot change the output (deterministic).
__global__ __launch_bounds__(512) void calib_kernel(
    const float* __restrict__ pc,         // (B, N, 3)
    const float* __restrict__ mask,       // (B, V, IMG, IMG)
    const float* __restrict__ bounds,     // (B, V, M, 2)
    const float* __restrict__ inv_param,  // (B, V, 4, 4)
    const float* __restrict__ proj_fine,  // (B, V, N, 2)
    const float* __restrict__ proj_finez, // (B, V, N)
    const int*   __restrict__ view_p,
    float*       __restrict__ out)        // (B, N, 3)
{
    const int view = *view_p;
    const int b = blockIdx.y;
    const int t = threadIdx.x;
    const int lane = t & 63;
    const int w = t >> 6;                 // wave id, 0..7

    __shared__ float4 s_e[Mm];            // packed (bdx, bdy, |bd|^2, j)  16 KB
    __shared__ float2 s_raw[Mm];          // raw (bx, by) by candidate j    8 KB
    __shared__ int s_start[1025];         // cell -> range start
    __shared__ int s_cnt[1024];           // counts, then cursors
    __shared__ int s_wtot[8];

    // ---- early-issue ALL per-point global loads (hide under binning) -----
    const int i = blockIdx.x * 512 + t;
    const size_t pf = (size_t)(b * Vv + view) * Nn + i;
    float2 pxy = reinterpret_cast<const float2*>(proj_fine)[pf];
    float z    = proj_finez[pf];
    const size_t ob = ((size_t)b * Nn + i) * 3;
    float pc0 = pc[ob], pc1 = pc[ob + 1], pc2 = pc[ob + 2];

    // ---------------- phase 1: bin this batch's candidates ----------------
    #pragma unroll
    for (int u = 0; u < 2; ++u) s_cnt[t + 512 * u] = 0;
    __syncthreads();

    const float* bnd = bounds + (size_t)(b * Vv + view) * Mm * 2;
    float bdx[2], bdy[2];
    int cell[2];
    #pragma unroll
    for (int u = 0; u < 2; ++u) {
        int j = t + 512 * u;
        float2 bxy = reinterpret_cast<const float2*>(bnd)[j];
        s_raw[j] = bxy;                   // raw mirror (exact loaded bits)
        bdx[u] = bxy.x / (float)IMG;      // exact IEEE div, matches ref
        bdy[u] = bxy.y / (float)IMG;
        int cx = min(G - 1, max(0, (int)(bdx[u] * (float)G)));
        int cy = min(G - 1, max(0, (int)(bdy[u] * (float)G)));
        cell[u] = cy * G + cx;
        atomicAdd(&s_cnt[cell[u]], 1);
    }

    // mask probe between hist and barrier: pxy has arrived; the probe's
    // latency hides under scan + scatter
    int i0 = (int)rintf(pxy.x);                 // round half-to-even
    int i1 = (int)rintf((float)IMG - pxy.y);
    int xi = min(max(i1 + 1, 0), IMG + 1);
    int yi = min(max(i0 + 1, 0), IMG + 1);
    float mval = 0.0f;
    if (xi >= 1 && xi <= IMG && yi >= 1 && yi <= IMG)
        mval = mask[((size_t)(b * Vv + view) * IMG + (xi - 1)) * IMG + (yi - 1)];
    const bool use_back = (mval == 0.0f);
    __syncthreads();

    // prefix sum over 1024 cells: 2 serial/thread + wave shfl-scan + fixup
    int c0 = s_cnt[2 * t], c1 = s_cnt[2 * t + 1];
    int psum = c0 + c1;
    int incl = psum;
    #pragma unroll
    for (int off = 1; off < 64; off <<= 1) {
        int v = __shfl_up(incl, off);
        if (lane >= off) incl += v;
    }
    if (lane == 63) s_wtot[w] = incl;
    __syncthreads();
    int basew = 0;
    #pragma unroll
    for (int ww = 0; ww < 8; ++ww) basew += (ww < w) ? s_wtot[ww] : 0;
    int base = basew + incl - psum;       // exclusive start of cell 2t
    s_start[2 * t] = base;
    s_start[2 * t + 1] = base + c0;
    if (t == 0) s_start[1024] = Mm;
    s_cnt[2 * t] = base;
    s_cnt[2 * t + 1] = base + c0;
    __syncthreads();

    // scatter (intra-cell order atomic-arbitrary; lex (d2,j) reduction makes
    // the final result order-invariant => deterministic output)
    #pragma unroll
    for (int u = 0; u < 2; ++u) {
        int j = t + 512 * u;
        int pos = atomicAdd(&s_cnt[cell[u]], 1);
        float nrm = __fadd_rn(__fmul_rn(bdx[u], bdx[u]), __fmul_rn(bdy[u], bdy[u]));
        s_e[pos] = make_float4(bdx[u], bdy[u], nrm, __int_as_float(j));
    }
    __syncthreads();

    // ---------------- phase 2: one thread = one point ----------------------
    if (use_back) {
        float ox = (float)i0 / (float)IMG;
        float oy = (float)i1 / (float)IMG;
        float o2 = __fadd_rn(__fmul_rn(ox, ox), __fmul_rn(oy, oy));
        // exact power-of-2 scale; d2 bits identical to the ref association
        float n2ox = __fmul_rn(-2.0f, ox);
        float n2oy = __fmul_rn(-2.0f, oy);

        int cx = min(G - 1, max(0, (int)(ox * (float)G)));
        int cy = min(G - 1, max(0, (int)(oy * (float)G)));

        float best = INFINITY;
        int   bj   = 0;

        // tier 1: full 5x5 window, serial per thread (visit order irrelevant)
        int x0 = max(cx - 2, 0), x1 = min(cx + 2, G - 1);
        int y0 = max(cy - 2, 0), y1 = min(cy + 2, G - 1);
        for (int yy = y0; yy <= y1; ++yy) {
            int rowb = yy * G;
            int e0 = s_start[rowb + x0];
            int e1 = s_start[rowb + x1 + 1];
            for (int e = e0; e < e1; ++e) {
                float4 cd = s_e[e];
                float dn = __fadd_rn(__fmul_rn(n2ox, cd.x), __fmul_rn(n2oy, cd.y));
                float d2 = __fadd_rn(__fadd_rn(o2, cd.z), dn);
                int   j  = __float_as_int(cd.w);
                bool better = (d2 < best) || (d2 == best && j < bj);
                best = better ? d2 : best;
                bj   = better ? j  : bj;
            }
        }

        // tier 2 (P~3e-6): serial ring walker, rings >= 3.
        // unvisited = Chebyshev cell-ring >= 3 => d >= 2h => d2 >= 4h^2-slop
        if (!(best < 4.0f * Hh * Hh - 1e-5f)) {
            for (int r = 3; r <= G; ++r) {
                float lim = (float)(r - 1) * Hh;
                if (best < lim * lim - 1e-5f) break;
                int rx0 = max(0, cx - r), rx1 = min(G - 1, cx + r);
                int ry0 = max(0, cy - r), ry1 = min(G - 1, cy + r);
                for (int yy = ry0; yy <= ry1; ++yy) {
                    bool yedge = (yy == cy - r) || (yy == cy + r);
                    for (int xx = rx0; xx <= rx1; ++xx) {
                        if (!yedge && xx != cx - r && xx != cx + r) continue;
                        int c = yy * G + xx;
                        int e0 = s_start[c], e1 = s_start[c + 1];
                        for (int e = e0; e < e1; ++e) {
                            float4 cd = s_e[e];
                            float dn = __fadd_rn(__fmul_rn(n2ox, cd.x), __fmul_rn(n2oy, cd.y));
                            float d2 = __fadd_rn(__fadd_rn(o2, cd.z), dn);
                            int   j  = __float_as_int(cd.w);
                            bool better = (d2 < best) || (d2 == best && j < bj);
                            best = better ? d2 : best;
                            bj   = better ? j  : bj;
                        }
                    }
                }
            }
        }

        // back-projection using the LDS raw mirror (same bits as bnd[2*bj])
        float2 nb = s_raw[bj];
        const float* ip = inv_param + (size_t)(b * Vv + view) * 16;
        float h0 = nb.x * z, h1 = nb.y * z;
        float r0 = h0 * ip[0] + h1 * ip[4] + z * ip[8]  + ip[12];
        float r1 = h0 * ip[1] + h1 * ip[5] + z * ip[9]  + ip[13];
        float r2 = h0 * ip[2] + h1 * ip[6] + z * ip[10] + ip[14];
        out[ob]     = r0;
        out[ob + 1] = r1;
        out[ob + 2] = r2;
    } else {
        out[ob]     = pc0;
        out[ob + 1] = pc1;
        out[ob + 2] = pc2;
    }
}

extern "C" void kernel_launch(void* const* d_in, const int* in_sizes, int n_in,
                              void* d_out, int out_size, void* d_ws, size_t ws_size,
                              hipStream_t stream) {
    const float* pc         = (const float*)d_in[0];
    const float* mask       = (const float*)d_in[1];
    const float* bounds     = (const float*)d_in[2];
    const float* inv_param  = (const float*)d_in[3];
    const float* proj_fine  = (const float*)d_in[4];
    const float* proj_finez = (const float*)d_in[5];
    const int*   view_p     = (const int*)d_in[6];
    float* out = (float*)d_out;

    dim3 grid(Nn / 512, Bb);              // 256 blocks = 1/CU, one launch
    calib_kernel<<<grid, 512, 0, stream>>>(pc, mask, bounds, inv_param,
                                           proj_fine, proj_finez, view_p, out);
}